// Round 2
// baseline (538.909 us; speedup 1.0000x reference)
//
#include <hip/hip_runtime.h>
#include <hip/hip_bf16.h>
#include <stdint.h>

// ---------------------------------------------------------------------------
// SelfAttention: B=4 S=2048 D=1024 H=16 HD=64. I/O dtype: FLOAT32.
// Pipeline (bf16 MFMA compute, fp32 accumulate):
//   0) cvt: x, Wq, Wk, Wv, Wo  f32 -> bf16   (biases stay f32, added in epilogue)
//   1) Q = xb@Wqb^T ; K = xb@Wkb^T           -> bf16 [B*S, D]
//   2) V = xb@Wvb^T stored TRANSPOSED as Vt[B,H,HD,S] bf16
//   3) flash attention -> Ctx bf16 [B*S, D]
//   4) out = Ctx@Wob^T + bo                  -> f32 (d_out)
// MFMA 16x16x32 bf16 layouts (HW-verified):
//   A: m=lane&15, k=(lane>>4)*8+j   B: n=lane&15, k=(lane>>4)*8+j
//   C/D: col=lane&15, row=(lane>>4)*4+reg
// ---------------------------------------------------------------------------

typedef __bf16 bf16;
typedef __bf16 bf16x8 __attribute__((ext_vector_type(8)));
typedef __bf16 bf16x4 __attribute__((ext_vector_type(4)));
typedef float  f32x4  __attribute__((ext_vector_type(4)));

#define MFMA_BF16(A, B, C) __builtin_amdgcn_mfma_f32_16x16x32_bf16(A, B, C, 0, 0, 0)

// ---------------------------------------------------------------------------
// Fused f32->bf16 conversion for 5 tensors. blockIdx.y selects the tensor.
// ---------------------------------------------------------------------------
__global__ __launch_bounds__(256) void cvt5(
    const float* __restrict__ s0, bf16* __restrict__ d0, int n0,
    const float* __restrict__ s1, bf16* __restrict__ d1, int n1,
    const float* __restrict__ s2, bf16* __restrict__ d2, int n2,
    const float* __restrict__ s3, bf16* __restrict__ d3, int n3,
    const float* __restrict__ s4, bf16* __restrict__ d4, int n4)
{
  const float* s; bf16* d; int n;
  switch (blockIdx.y) {
    case 0: s = s0; d = d0; n = n0; break;
    case 1: s = s1; d = d1; n = n1; break;
    case 2: s = s2; d = d2; n = n2; break;
    case 3: s = s3; d = d3; n = n3; break;
    default: s = s4; d = d4; n = n4; break;
  }
  const int stride = gridDim.x * blockDim.x * 4;
  for (int i = (blockIdx.x * blockDim.x + threadIdx.x) * 4; i < n; i += stride) {
    const float4 v = *(const float4*)(s + i);
    bf16x4 o;
    o[0] = (bf16)v.x; o[1] = (bf16)v.y; o[2] = (bf16)v.z; o[3] = (bf16)v.w;
    *(bf16x4*)(d + i) = o;
  }
}

// ---------------------------------------------------------------------------
// GEMM: Y[m,n] = sum_k X[m,k]*W[n,k] + bias[n].  M%128==0, N%128==0, K%64==0.
// mode 0: bf16 Y row-major [M,N].  mode 1: bf16 V-transpose [B,H,HD,S].
// mode 2: f32 Y row-major [M,N].
// LDS: 16B octet blocks at m*8 + (ko ^ (m&7)) (XOR swizzle: conflict-free
// b128 frag reads AND conflict-free staging writes).
// ---------------------------------------------------------------------------
__global__ __launch_bounds__(256) void gemm_bt(
    const bf16* __restrict__ X, const bf16* __restrict__ W,
    const float* __restrict__ bias, bf16* __restrict__ Yb,
    float* __restrict__ Yf, int M, int N, int K, int mode)
{
  __shared__ alignas(16) bf16 As[8192];   // 128 rows x 64 k (16KB)
  __shared__ alignas(16) bf16 Bs[8192];

  const int tid  = threadIdx.x;
  const int lane = tid & 63;
  const int wv   = tid >> 6;
  const int l15  = lane & 15;
  const int quad = lane >> 4;
  const int wm   = (wv >> 1) * 64;   // wave's 64x64 quadrant
  const int wn   = (wv & 1) * 64;
  const int nbase = blockIdx.x * 128;
  const int mbase = blockIdx.y * 128;

  f32x4 acc[4][4];
  #pragma unroll
  for (int i = 0; i < 4; ++i)
    #pragma unroll
    for (int j = 0; j < 4; ++j)
      acc[i][j] = (f32x4){0.f, 0.f, 0.f, 0.f};

  const int srow = tid >> 3;   // staging: 32 rows per pass, 8 octets/row
  const int sko  = tid & 7;

  for (int kb = 0; kb < K; kb += 64) {
    #pragma unroll
    for (int i = 0; i < 4; ++i) {
      const int m = i * 32 + srow;
      const bf16x8 va = *(const bf16x8*)(X + (size_t)(mbase + m) * K + kb + sko * 8);
      *(bf16x8*)(As + (m * 8 + (sko ^ (m & 7))) * 8) = va;
      const bf16x8 vb = *(const bf16x8*)(W + (size_t)(nbase + m) * K + kb + sko * 8);
      *(bf16x8*)(Bs + (m * 8 + (sko ^ (m & 7))) * 8) = vb;
    }
    __syncthreads();
    #pragma unroll
    for (int ks = 0; ks < 2; ++ks) {
      bf16x8 af[4], bfr[4];
      #pragma unroll
      for (int t = 0; t < 4; ++t) {
        const int ma = wm + t * 16 + l15;
        af[t]  = *(const bf16x8*)(As + (ma * 8 + ((ks * 4 + quad) ^ (ma & 7))) * 8);
        const int nb = wn + t * 16 + l15;
        bfr[t] = *(const bf16x8*)(Bs + (nb * 8 + ((ks * 4 + quad) ^ (nb & 7))) * 8);
      }
      #pragma unroll
      for (int i = 0; i < 4; ++i)
        #pragma unroll
        for (int j = 0; j < 4; ++j)
          acc[i][j] = MFMA_BF16(af[i], bfr[j], acc[i][j]);
    }
    __syncthreads();
  }

  #pragma unroll
  for (int i = 0; i < 4; ++i) {
    const int row0 = mbase + wm + i * 16 + quad * 4;
    #pragma unroll
    for (int j = 0; j < 4; ++j) {
      const int col = nbase + wn + j * 16 + l15;
      const float bv = bias[col];
      #pragma unroll
      for (int r = 0; r < 4; ++r) {
        const float v = acc[i][j][r] + bv;
        const int row = row0 + r;
        if (mode == 0) {
          Yb[(size_t)row * N + col] = (bf16)v;
        } else if (mode == 1) {
          // row = b*2048+s ; col = h*64+hd ; Vt[((b*16+h)*64+hd)*2048 + s]
          const int bb = row >> 11, s  = row & 2047;
          const int hh = col >> 6,  hd = col & 63;
          Yb[(size_t)((bb * 16 + hh) * 64 + hd) * 2048 + s] = (bf16)v;
        } else {
          Yf[(size_t)row * N + col] = v;
        }
      }
    }
  }
}

// ---------------------------------------------------------------------------
// Flash attention. Block = (qtile of 64, h, b); wave = 16 q-rows.
// 32-key chunks: stage K[32][64] (stride 80) and Vt[64][32] (stride 40);
// QK^T via 2 MFMAs per 16-key subtile; online softmax per q-row (row =
// quad*4+r, reduce across the 16 lanes of the quad-group); P -> LDS
// (C-layout write, A-layout 16B read); PV MFMA.
// ---------------------------------------------------------------------------
__global__ __launch_bounds__(256) void attn(
    const bf16* __restrict__ Qb, const bf16* __restrict__ Kb,
    const bf16* __restrict__ Vt, bf16* __restrict__ Ob)
{
  constexpr int S = 2048, D = 1024;
  __shared__ alignas(16) bf16 KsL[32 * 80];
  __shared__ alignas(16) bf16 VsL[64 * 40];
  __shared__ alignas(16) bf16 PsL[4 * 16 * 40];

  const int tid  = threadIdx.x;
  const int lane = tid & 63;
  const int wv   = tid >> 6;
  const int l15  = lane & 15;
  const int quad = lane >> 4;
  const int b = blockIdx.z, h = blockIdx.y;
  const int qbase = blockIdx.x * 64;

  // Q fragments (A-layout), pre-scaled by 1/sqrt(64)=0.125 (exact in bf16)
  bf16x8 qf[2];
  {
    const int sq = qbase + wv * 16 + l15;
    const bf16* qp = Qb + (size_t)(b * S + sq) * D + h * 64 + quad * 8;
    qf[0] = *(const bf16x8*)qp;
    qf[1] = *(const bf16x8*)(qp + 32);
    #pragma unroll
    for (int c = 0; c < 2; ++c)
      #pragma unroll
      for (int e = 0; e < 8; ++e)
        qf[c][e] = (bf16)((float)qf[c][e] * 0.125f);
  }

  float mrun[4], lrun[4];
  f32x4 o[4];
  #pragma unroll
  for (int r = 0; r < 4; ++r) { mrun[r] = -__builtin_inff(); lrun[r] = 0.f; }
  #pragma unroll
  for (int nt = 0; nt < 4; ++nt) o[nt] = (f32x4){0.f, 0.f, 0.f, 0.f};

  const int skey = tid >> 3, skoff = (tid & 7) * 8;  // K staging map
  const int shd  = tid >> 2, svoff = (tid & 3) * 8;  // V staging map
  const bf16* kp = Kb + (size_t)b * S * D + h * 64;
  const bf16* vp = Vt + (size_t)((b * 16 + h) * 64) * S;

  for (int kc = 0; kc < S; kc += 32) {
    {
      const bf16x8 kv = *(const bf16x8*)(kp + (size_t)(kc + skey) * D + skoff);
      *(bf16x8*)(KsL + skey * 80 + skoff) = kv;
      const bf16x8 vv = *(const bf16x8*)(vp + (size_t)shd * S + kc + svoff);
      *(bf16x8*)(VsL + shd * 40 + svoff) = vv;
    }
    __syncthreads();

    // scores: rows quad*4+r, cols kt*16+l15
    f32x4 sc[2];
    #pragma unroll
    for (int kt = 0; kt < 2; ++kt) {
      const bf16x8 kf0 = *(const bf16x8*)(KsL + (kt * 16 + l15) * 80 + quad * 8);
      const bf16x8 kf1 = *(const bf16x8*)(KsL + (kt * 16 + l15) * 80 + 32 + quad * 8);
      f32x4 s = (f32x4){0.f, 0.f, 0.f, 0.f};
      s = MFMA_BF16(qf[0], kf0, s);
      s = MFMA_BF16(qf[1], kf1, s);
      sc[kt] = s;
    }

    #pragma unroll
    for (int r = 0; r < 4; ++r) {
      float rmax = fmaxf(sc[0][r], sc[1][r]);
      #pragma unroll
      for (int msk = 8; msk >= 1; msk >>= 1)
        rmax = fmaxf(rmax, __shfl_xor(rmax, msk, 64));
      const float mnew  = fmaxf(mrun[r], rmax);
      const float alpha = __expf(mrun[r] - mnew);
      const float p0 = __expf(sc[0][r] - mnew);
      const float p1 = __expf(sc[1][r] - mnew);
      float psum = p0 + p1;
      #pragma unroll
      for (int msk = 8; msk >= 1; msk >>= 1)
        psum += __shfl_xor(psum, msk, 64);
      lrun[r] = lrun[r] * alpha + psum;
      mrun[r] = mnew;
      #pragma unroll
      for (int nt = 0; nt < 4; ++nt) o[nt][r] *= alpha;
      PsL[wv * 640 + (quad * 4 + r) * 40 + l15]      = (bf16)p0;
      PsL[wv * 640 + (quad * 4 + r) * 40 + 16 + l15] = (bf16)p1;
    }
    __syncthreads();   // debug-safety: order P stores before A-layout loads

    // P (A-layout) and V (B-layout) fragments; accumulate O
    const bf16x8 pf = *(const bf16x8*)(PsL + wv * 640 + l15 * 40 + quad * 8);
    #pragma unroll
    for (int nt = 0; nt < 4; ++nt) {
      const bf16x8 vf = *(const bf16x8*)(VsL + (nt * 16 + l15) * 40 + quad * 8);
      o[nt] = MFMA_BF16(pf, vf, o[nt]);
    }
    __syncthreads();
  }

  #pragma unroll
  for (int nt = 0; nt < 4; ++nt)
    #pragma unroll
    for (int r = 0; r < 4; ++r) {
      const int srow = qbase + wv * 16 + quad * 4 + r;
      Ob[(size_t)(b * S + srow) * D + h * 64 + nt * 16 + l15] =
          (bf16)(o[nt][r] / lrun[r]);
    }
}

// ---------------------------------------------------------------------------
extern "C" void kernel_launch(void* const* d_in, const int* in_sizes, int n_in,
                              void* d_out, int out_size, void* d_ws, size_t ws_size,
                              hipStream_t stream)
{
  const float* x  = (const float*)d_in[0];
  const float* Wq = (const float*)d_in[1];
  const float* bq = (const float*)d_in[2];
  const float* Wk = (const float*)d_in[3];
  const float* bk = (const float*)d_in[4];
  const float* Wv = (const float*)d_in[5];
  const float* bv = (const float*)d_in[6];
  const float* Wo = (const float*)d_in[7];
  const float* bo = (const float*)d_in[8];
  float* out = (float*)d_out;

  const size_t NX = (size_t)8192 * 1024;   // x / Q / K / V / Ctx element count
  const size_t NW = (size_t)1024 * 1024;   // weight element count

  bf16* xb  = (bf16*)d_ws;
  bf16* Wqb = xb  + NX;
  bf16* Wkb = Wqb + NW;
  bf16* Wvb = Wkb + NW;
  bf16* Wob = Wvb + NW;
  bf16* Qb  = Wob + NW;
  bf16* Kb  = Qb  + NX;
  bf16* Vt  = Kb  + NX;   // transposed [B,H,HD,S]
  bf16* Ctx = Vt  + NX;   // total: 5*NX + 4*NW bf16 = ~92 MB

  dim3 bc(256, 1, 1);
  hipLaunchKernelGGL(cvt5, dim3(1024, 5, 1), bc, 0, stream,
                     x, xb, (int)NX, Wq, Wqb, (int)NW, Wk, Wkb, (int)NW,
                     Wv, Wvb, (int)NW, Wo, Wob, (int)NW);

  dim3 gg(8, 64, 1);
  hipLaunchKernelGGL(gemm_bt, gg, bc, 0, stream, xb, Wqb, bq, Qb, (float*)nullptr, 8192, 1024, 1024, 0);
  hipLaunchKernelGGL(gemm_bt, gg, bc, 0, stream, xb, Wkb, bk, Kb, (float*)nullptr, 8192, 1024, 1024, 0);
  hipLaunchKernelGGL(gemm_bt, gg, bc, 0, stream, xb, Wvb, bv, Vt, (float*)nullptr, 8192, 1024, 1024, 1);
  dim3 ga(32, 16, 4);
  hipLaunchKernelGGL(attn, ga, bc, 0, stream, Qb, Kb, Vt, Ctx);
  hipLaunchKernelGGL(gemm_bt, gg, bc, 0, stream, Ctx, Wob, bo, (bf16*)nullptr, out, 8192, 1024, 1024, 2);
}

// Round 4
// 333.632 us; speedup vs baseline: 1.6153x; 1.6153x over previous
//
#include <hip/hip_runtime.h>
#include <hip/hip_bf16.h>
#include <stdint.h>

// ---------------------------------------------------------------------------
// SelfAttention: B=4 S=2048 D=1024 H=16 HD=64. I/O dtype: FLOAT32.
// Pipeline (bf16 MFMA compute, fp32 accumulate):
//   0) cvt: x, Wq, Wk, Wv, Wo  f32 -> bf16
//   1) Q = (x@Wq^T+bq)*0.125*log2e  -> bf16 [B*S, D]   (scale folded in)
//      K = x@Wk^T+bk               -> bf16 [B*S, D]
//   2) V = x@Wv^T+bv stored TRANSPOSED as Vt[B,H,HD,S] bf16
//   3) flash attention (transposed-S formulation) -> Ctx bf16 [B*S, D]
//   4) out = Ctx@Wo^T + bo -> f32 (d_out)
// MFMA 16x16x32 bf16 layouts (HW-verified):
//   A: m=lane&15, k=(lane>>4)*8+j   B: n=lane&15, k=(lane>>4)*8+j
//   C/D: col=lane&15, row=(lane>>4)*4+reg
// exp2 via __builtin_amdgcn_exp2f (v_exp_f32) — plain __exp2f collides with
// glibc math.h macros in this toolchain (R3 compile failure).
// ---------------------------------------------------------------------------

typedef __bf16 bf16;
typedef __bf16 bf16x8 __attribute__((ext_vector_type(8)));
typedef __bf16 bf16x4 __attribute__((ext_vector_type(4)));
typedef float  f32x4  __attribute__((ext_vector_type(4)));

#define MFMA_BF16(A, B, C) __builtin_amdgcn_mfma_f32_16x16x32_bf16(A, B, C, 0, 0, 0)
#define EXP2F(x) __builtin_amdgcn_exp2f(x)

// ---------------------------------------------------------------------------
__global__ __launch_bounds__(256) void cvt5(
    const float* __restrict__ s0, bf16* __restrict__ d0, int n0,
    const float* __restrict__ s1, bf16* __restrict__ d1, int n1,
    const float* __restrict__ s2, bf16* __restrict__ d2, int n2,
    const float* __restrict__ s3, bf16* __restrict__ d3, int n3,
    const float* __restrict__ s4, bf16* __restrict__ d4, int n4)
{
  const float* s; bf16* d; int n;
  switch (blockIdx.y) {
    case 0: s = s0; d = d0; n = n0; break;
    case 1: s = s1; d = d1; n = n1; break;
    case 2: s = s2; d = d2; n = n2; break;
    case 3: s = s3; d = d3; n = n3; break;
    default: s = s4; d = d4; n = n4; break;
  }
  const int stride = gridDim.x * blockDim.x * 4;
  for (int i = (blockIdx.x * blockDim.x + threadIdx.x) * 4; i < n; i += stride) {
    const float4 v = *(const float4*)(s + i);
    bf16x4 o;
    o[0] = (bf16)v.x; o[1] = (bf16)v.y; o[2] = (bf16)v.z; o[3] = (bf16)v.w;
    *(bf16x4*)(d + i) = o;
  }
}

// ---------------------------------------------------------------------------
// GEMM: Y[m,n] = (sum_k X[m,k]*W[n,k] + bias[n]) * scale.
// mode 0: bf16 Y row-major. mode 1: bf16 V-transpose [B,H,HD,S]. mode 2: f32 Y.
// ---------------------------------------------------------------------------
__global__ __launch_bounds__(256) void gemm_bt(
    const bf16* __restrict__ X, const bf16* __restrict__ W,
    const float* __restrict__ bias, bf16* __restrict__ Yb,
    float* __restrict__ Yf, int M, int N, int K, int mode, float scale)
{
  __shared__ alignas(16) bf16 As[8192];   // 128 rows x 64 k (16KB)
  __shared__ alignas(16) bf16 Bs[8192];

  const int tid  = threadIdx.x;
  const int lane = tid & 63;
  const int wv   = tid >> 6;
  const int l15  = lane & 15;
  const int quad = lane >> 4;
  const int wm   = (wv >> 1) * 64;
  const int wn   = (wv & 1) * 64;
  const int nbase = blockIdx.x * 128;
  const int mbase = blockIdx.y * 128;

  f32x4 acc[4][4];
  #pragma unroll
  for (int i = 0; i < 4; ++i)
    #pragma unroll
    for (int j = 0; j < 4; ++j)
      acc[i][j] = (f32x4){0.f, 0.f, 0.f, 0.f};

  const int srow = tid >> 3;
  const int sko  = tid & 7;

  for (int kb = 0; kb < K; kb += 64) {
    #pragma unroll
    for (int i = 0; i < 4; ++i) {
      const int m = i * 32 + srow;
      const bf16x8 va = *(const bf16x8*)(X + (size_t)(mbase + m) * K + kb + sko * 8);
      *(bf16x8*)(As + (m * 8 + (sko ^ (m & 7))) * 8) = va;
      const bf16x8 vb = *(const bf16x8*)(W + (size_t)(nbase + m) * K + kb + sko * 8);
      *(bf16x8*)(Bs + (m * 8 + (sko ^ (m & 7))) * 8) = vb;
    }
    __syncthreads();
    #pragma unroll
    for (int ks = 0; ks < 2; ++ks) {
      bf16x8 af[4], bfr[4];
      #pragma unroll
      for (int t = 0; t < 4; ++t) {
        const int ma = wm + t * 16 + l15;
        af[t]  = *(const bf16x8*)(As + (ma * 8 + ((ks * 4 + quad) ^ (ma & 7))) * 8);
        const int nb = wn + t * 16 + l15;
        bfr[t] = *(const bf16x8*)(Bs + (nb * 8 + ((ks * 4 + quad) ^ (nb & 7))) * 8);
      }
      #pragma unroll
      for (int i = 0; i < 4; ++i)
        #pragma unroll
        for (int j = 0; j < 4; ++j)
          acc[i][j] = MFMA_BF16(af[i], bfr[j], acc[i][j]);
    }
    __syncthreads();
  }

  #pragma unroll
  for (int i = 0; i < 4; ++i) {
    const int row0 = mbase + wm + i * 16 + quad * 4;
    #pragma unroll
    for (int j = 0; j < 4; ++j) {
      const int col = nbase + wn + j * 16 + l15;
      const float bv = bias[col];
      #pragma unroll
      for (int r = 0; r < 4; ++r) {
        const float v = (acc[i][j][r] + bv) * scale;
        const int row = row0 + r;
        if (mode == 0) {
          Yb[(size_t)row * N + col] = (bf16)v;
        } else if (mode == 1) {
          const int bb = row >> 11, s  = row & 2047;
          const int hh = col >> 6,  hd = col & 63;
          Yb[(size_t)((bb * 16 + hh) * 64 + hd) * 2048 + s] = (bf16)v;
        } else {
          Yf[(size_t)row * N + col] = v;
        }
      }
    }
  }
}

// ---------------------------------------------------------------------------
// Flash attention, transposed-S formulation.
// Block = 256 threads = 4 waves; wave owns 64 q (4 q-tiles of 16, q=l15 col).
// Per 64-key chunk (double-buffered LDS, 1 barrier/chunk):
//   S^T = K@Q^T  (A=K with PERMUTED key rows: key = 8*(l15>>2)+4*kt+(l15&3),
//                 so C regs of lane (q0,l15) hold keys 8*q0+j -> P^T B-frags
//                 are lane-local, no transpose)
//   softmax: reg-space max (+2 shuffles), exp2, quad-partial l
//   O^T += V^T@P^T  (V A-frags plain order from Vt, contiguous 16B)
// Epilogue: l cross-quad reduce, O^T regs (hd=q0*4+r consecutive) -> 8B stores.
// ---------------------------------------------------------------------------
__global__ __launch_bounds__(256, 2) void attn(
    const bf16* __restrict__ Qb, const bf16* __restrict__ Kb,
    const bf16* __restrict__ Vt, bf16* __restrict__ Ob)
{
  constexpr int S = 2048, D = 1024;
  __shared__ alignas(16) bf16 Ks[2][4096];  // [key 0..63][d octet 0..7 swz]
  __shared__ alignas(16) bf16 Vs[2][4096];  // [hd 0..63][key octet 0..7 swz]

  const int tid  = threadIdx.x;
  const int lane = tid & 63;
  const int wv   = tid >> 6;
  const int l15  = lane & 15;
  const int q0   = lane >> 4;
  const int b = blockIdx.z, h = blockIdx.y;
  const int qblk = blockIdx.x * 256 + wv * 64;

  // Q B-frags (Q already scaled by 0.125*log2e in its GEMM epilogue)
  bf16x8 qf[4][2];
  #pragma unroll
  for (int qt = 0; qt < 4; ++qt)
    #pragma unroll
    for (int dh = 0; dh < 2; ++dh)
      qf[qt][dh] = *(const bf16x8*)(
          Qb + (size_t)(b * S + qblk + qt * 16 + l15) * D + h * 64 + dh * 32 + q0 * 8);

  float mrun[4], lrun[4];
  f32x4 o[4][4];   // o[ht][qt]
  #pragma unroll
  for (int qt = 0; qt < 4; ++qt) { mrun[qt] = -__builtin_inff(); lrun[qt] = 0.f; }
  #pragma unroll
  for (int ht = 0; ht < 4; ++ht)
    #pragma unroll
    for (int qt = 0; qt < 4; ++qt)
      o[ht][qt] = (f32x4){0.f, 0.f, 0.f, 0.f};

  // staging: thread -> (row = lane, octets wv and wv+4); 2-way writes
  const int skey = lane;
  const int so   = wv;
  const bf16* kg = Kb + (size_t)(b * S) * D + h * 64;
  const bf16* vg = Vt + (size_t)((b * 16 + h) * 64) * S;
  const int swk = (skey & 3) | (((skey >> 3) & 1) << 2);

  // frag-read constants
  const int kla = 8 * (l15 >> 2) + (l15 & 3);            // permuted key base
  const int swa = (l15 & 3) | (((l15 >> 2) & 1) << 2);   // K-read swizzle
  const int swv = l15 & 7;                               // V-read swizzle

#define STAGE(KC, BUF)                                                        \
  {                                                                           \
    const bf16* krow = kg + (size_t)((KC) + skey) * D;                        \
    const bf16x8 k0 = *(const bf16x8*)(krow + so * 8);                        \
    const bf16x8 k1 = *(const bf16x8*)(krow + (so + 4) * 8);                  \
    *(bf16x8*)(&Ks[BUF][(skey * 8 + (so ^ swk)) * 8]) = k0;                   \
    *(bf16x8*)(&Ks[BUF][(skey * 8 + ((so + 4) ^ swk)) * 8]) = k1;             \
    const bf16* vrow = vg + (size_t)skey * S + (KC);                          \
    const bf16x8 v0 = *(const bf16x8*)(vrow + so * 8);                        \
    const bf16x8 v1 = *(const bf16x8*)(vrow + (so + 4) * 8);                  \
    *(bf16x8*)(&Vs[BUF][(skey * 8 + (so ^ (skey & 7))) * 8]) = v0;            \
    *(bf16x8*)(&Vs[BUF][(skey * 8 + ((so + 4) ^ (skey & 7))) * 8]) = v1;      \
  }

  STAGE(0, 0);

  for (int kc = 0, it = 0; kc < S; kc += 64, ++it) {
    const int cur = it & 1;
    __syncthreads();
    if (kc + 64 < S) STAGE(kc + 64, cur ^ 1);

    // ---- S^T = K @ Q^T : sc[qt][kt], C col = q, row-regs = keys 8q0+... ----
    f32x4 sc[4][4];
    #pragma unroll
    for (int kt = 0; kt < 4; ++kt) {
      const int key = kla + 4 * (kt & 1) + 32 * (kt >> 1);
      const bf16x8 kf0 = *(const bf16x8*)(&Ks[cur][(key * 8 + (q0 ^ swa)) * 8]);
      const bf16x8 kf1 = *(const bf16x8*)(&Ks[cur][(key * 8 + ((q0 + 4) ^ swa)) * 8]);
      #pragma unroll
      for (int qt = 0; qt < 4; ++qt) {
        f32x4 s = MFMA_BF16(kf0, qf[qt][0], ((f32x4){0.f, 0.f, 0.f, 0.f}));
        sc[qt][kt] = MFMA_BF16(kf1, qf[qt][1], s);
      }
    }

    // ---- online softmax (register space) + pack P^T B-frags ----
    bf16x8 pb[4][2];
    #pragma unroll
    for (int qt = 0; qt < 4; ++qt) {
      float cmax = sc[qt][0][0];
      #pragma unroll
      for (int kt = 0; kt < 4; ++kt)
        #pragma unroll
        for (int r = 0; r < 4; ++r)
          cmax = fmaxf(cmax, sc[qt][kt][r]);
      cmax = fmaxf(cmax, __shfl_xor(cmax, 16, 64));
      cmax = fmaxf(cmax, __shfl_xor(cmax, 32, 64));
      const float mnew  = fmaxf(mrun[qt], cmax);
      const float alpha = EXP2F(mrun[qt] - mnew);
      mrun[qt] = mnew;
      float ps = 0.f;
      #pragma unroll
      for (int kt = 0; kt < 4; ++kt)
        #pragma unroll
        for (int r = 0; r < 4; ++r) {
          const float p = EXP2F(sc[qt][kt][r] - mnew);
          ps += p;
          pb[qt][kt >> 1][(kt & 1) * 4 + r] = (bf16)p;
        }
      lrun[qt] = lrun[qt] * alpha + ps;   // quad-partial sum
      #pragma unroll
      for (int ht = 0; ht < 4; ++ht) {
        o[ht][qt][0] *= alpha; o[ht][qt][1] *= alpha;
        o[ht][qt][2] *= alpha; o[ht][qt][3] *= alpha;
      }
    }

    // ---- O^T += V^T @ P^T ----
    #pragma unroll
    for (int ht = 0; ht < 4; ++ht) {
      const int row = ht * 16 + l15;
      const bf16x8 vf0 = *(const bf16x8*)(&Vs[cur][(row * 8 + (q0 ^ swv)) * 8]);
      const bf16x8 vf1 = *(const bf16x8*)(&Vs[cur][(row * 8 + ((q0 + 4) ^ swv)) * 8]);
      #pragma unroll
      for (int qt = 0; qt < 4; ++qt) {
        o[ht][qt] = MFMA_BF16(vf0, pb[qt][0], o[ht][qt]);
        o[ht][qt] = MFMA_BF16(vf1, pb[qt][1], o[ht][qt]);
      }
    }
  }
#undef STAGE

  // ---- epilogue: finish l, normalize, store (hd consecutive per reg) ----
  #pragma unroll
  for (int qt = 0; qt < 4; ++qt) {
    float l = lrun[qt];
    l += __shfl_xor(l, 16, 64);
    l += __shfl_xor(l, 32, 64);
    const float inv = 1.0f / l;
    bf16* orow = Ob + (size_t)(b * S + qblk + qt * 16 + l15) * D + h * 64 + q0 * 4;
    #pragma unroll
    for (int ht = 0; ht < 4; ++ht) {
      bf16x4 w;
      w[0] = (bf16)(o[ht][qt][0] * inv);
      w[1] = (bf16)(o[ht][qt][1] * inv);
      w[2] = (bf16)(o[ht][qt][2] * inv);
      w[3] = (bf16)(o[ht][qt][3] * inv);
      *(bf16x4*)(orow + ht * 16) = w;
    }
  }
}

// ---------------------------------------------------------------------------
extern "C" void kernel_launch(void* const* d_in, const int* in_sizes, int n_in,
                              void* d_out, int out_size, void* d_ws, size_t ws_size,
                              hipStream_t stream)
{
  const float* x  = (const float*)d_in[0];
  const float* Wq = (const float*)d_in[1];
  const float* bq = (const float*)d_in[2];
  const float* Wk = (const float*)d_in[3];
  const float* bk = (const float*)d_in[4];
  const float* Wv = (const float*)d_in[5];
  const float* bv = (const float*)d_in[6];
  const float* Wo = (const float*)d_in[7];
  const float* bo = (const float*)d_in[8];
  float* out = (float*)d_out;

  const size_t NX = (size_t)8192 * 1024;
  const size_t NW = (size_t)1024 * 1024;

  bf16* xb  = (bf16*)d_ws;
  bf16* Wqb = xb  + NX;
  bf16* Wkb = Wqb + NW;
  bf16* Wvb = Wkb + NW;
  bf16* Wob = Wvb + NW;
  bf16* Qb  = Wob + NW;
  bf16* Kb  = Qb  + NX;
  bf16* Vt  = Kb  + NX;
  bf16* Ctx = Vt  + NX;

  const float QSCALE = 0.18033688011112042f;  // 0.125 * log2(e)

  dim3 bc(256, 1, 1);
  hipLaunchKernelGGL(cvt5, dim3(1024, 5, 1), bc, 0, stream,
                     x, xb, (int)NX, Wq, Wqb, (int)NW, Wk, Wkb, (int)NW,
                     Wv, Wvb, (int)NW, Wo, Wob, (int)NW);

  dim3 gg(8, 64, 1);
  hipLaunchKernelGGL(gemm_bt, gg, bc, 0, stream, xb, Wqb, bq, Qb, (float*)nullptr, 8192, 1024, 1024, 0, QSCALE);
  hipLaunchKernelGGL(gemm_bt, gg, bc, 0, stream, xb, Wkb, bk, Kb, (float*)nullptr, 8192, 1024, 1024, 0, 1.0f);
  hipLaunchKernelGGL(gemm_bt, gg, bc, 0, stream, xb, Wvb, bv, Vt, (float*)nullptr, 8192, 1024, 1024, 1, 1.0f);
  dim3 ga(8, 16, 4);
  hipLaunchKernelGGL(attn, ga, bc, 0, stream, Qb, Kb, Vt, Ctx);
  hipLaunchKernelGGL(gemm_bt, gg, bc, 0, stream, Ctx, Wob, bo, (bf16*)nullptr, out, 8192, 1024, 1024, 2, 1.0f);
}